// Round 2
// baseline (218.357 us; speedup 1.0000x reference)
//
#include <hip/hip_runtime.h>
#include <math.h>

#define BATCH  8
#define SEQ    8192
#define DMODEL 256
#define DSTATE 2
#define CHUNKS 512   // C
#define CLEN   16    // L = SEQ / C
#define CPAD   1040  // floats per (b,c) block: 1024 data + 16 pad (16B-aligned rows)
#define NSEG   16    // segments per batch-scan
#define SEGLEN 32    // chunks per segment = CHUNKS / NSEG

typedef float floatx4 __attribute__((ext_vector_type(4)));  // nontemporal-store-safe

// ---------------------------------------------------------------------------
// Layouts:
//   x, y : [B][T][D] fp32
//   params: [D][S] fp32 (S=2)
//   E / Hin workspace: [B][C][CPAD] floats (first 1024 used)
//     lane d4 = d/4 owns 16 floats: j=0..3 -> (s0re, s0im, s1re, s1im)
//     scan slot r = d4*8 + j*2 + s -> float2 at float-offset 2r.
//   G: [B][NSEG][512] float2 segment aggregates (512 KB)
// Recurrence: h[t] = a h[t-1] + B x[t], a = e^{lm}(cos ph + i sin ph)
// y[t,d] = sum_s Re(C h) + D_diag x
// ---------------------------------------------------------------------------

// Kernel 1: per-chunk local end state (zero init).
// 1024 blocks x 256 threads; wave w -> chunk (b, cg*4+w); lane -> d4.
// All 16 x-rows pre-issued (float4 xv[16]) so >=16 wave-loads stay in flight
// across the serial recurrence (round-1 was latency-bound at 2.3 TB/s).
__global__ __launch_bounds__(256, 3)
void ssm_chunk_state(const float* __restrict__ x,
                     const float* __restrict__ lam,
                     const float* __restrict__ aph,
                     const float* __restrict__ Bre,
                     const float* __restrict__ Bim,
                     float* __restrict__ E) {
    const int lane = threadIdx.x & 63;
    const int w    = threadIdx.x >> 6;
    const int bid  = blockIdx.x;
    const int b    = bid >> 7;
    const int c    = ((bid & 127) << 2) + w;
    const int d0   = lane * 4;

    // pre-issue all 16 row loads (compile-time indexed -> VGPRs, MLP=16)
    const float* xp = x + ((size_t)b * SEQ + (size_t)c * CLEN) * DMODEL + d0;
    float4 xv[CLEN];
#pragma unroll
    for (int t = 0; t < CLEN; ++t)
        xv[t] = *reinterpret_cast<const float4*>(xp + (size_t)t * DMODEL);

    float ar[4][2], ai[4][2], br[4][2], bi[4][2];
#pragma unroll
    for (int j = 0; j < 4; ++j) {
        const int d = d0 + j;
#pragma unroll
        for (int s = 0; s < 2; ++s) {
            const float lm = lam[d * 2 + s];
            const float ph = aph[d * 2 + s];
            const float m  = expf(lm);
            ar[j][s] = m * cosf(ph);
            ai[j][s] = m * sinf(ph);
            br[j][s] = Bre[d * 2 + s];
            bi[j][s] = Bim[d * 2 + s];
        }
    }

    float hr[4][2] = {}, hi[4][2] = {};
#pragma unroll
    for (int t = 0; t < CLEN; ++t) {
        const float xj[4] = {xv[t].x, xv[t].y, xv[t].z, xv[t].w};
#pragma unroll
        for (int j = 0; j < 4; ++j) {
#pragma unroll
            for (int s = 0; s < 2; ++s) {
                const float nr = fmaf(ar[j][s], hr[j][s],
                                 fmaf(-ai[j][s], hi[j][s], br[j][s] * xj[j]));
                const float ni = fmaf(ar[j][s], hi[j][s],
                                 fmaf( ai[j][s], hr[j][s], bi[j][s] * xj[j]));
                hr[j][s] = nr;
                hi[j][s] = ni;
            }
        }
    }

    float* ep = E + ((size_t)b * CHUNKS + c) * CPAD + lane * 16;
#pragma unroll
    for (int j = 0; j < 4; ++j) {
        float4 v;
        v.x = hr[j][0]; v.y = hi[j][0];
        v.z = hr[j][1]; v.w = hi[j][1];
        reinterpret_cast<float4*>(ep)[j] = v;
    }
}

// Kernel 2a: segment aggregates, fully coalesced.
// 128 blocks (b, seg) x 512 threads; thread owns scan slot r, serially folds
// its segment's 32 chunk states. Each chunk access = 4 KB contiguous per block.
// G[b][seg][r] = sum_i A_L^(31-i) e[seg*32+i].
__global__ __launch_bounds__(512, 4)
void ssm_seg_aggregate(const float* __restrict__ E,
                       const float* __restrict__ lam,
                       const float* __restrict__ aph,
                       float* __restrict__ G) {
    const int b   = blockIdx.x >> 4;
    const int seg = blockIdx.x & (NSEG - 1);
    const int r   = threadIdx.x;
    const int d   = (r >> 3) * 4 + ((r >> 1) & 3);
    const int s   = r & 1;

    const double lm = (double)lam[d * 2 + s];
    const double ph = (double)aph[d * 2 + s];
    const double mL = exp(lm * (double)CLEN);
    const double pL = ph * (double)CLEN;
    const float Ar = (float)(mL * cos(pL));   // A_L = a^CLEN
    const float Ai = (float)(mL * sin(pL));

    const size_t ebase = ((size_t)b * CHUNKS + (size_t)seg * SEGLEN) * CPAD + (size_t)r * 2;

    float2 e[SEGLEN];
#pragma unroll
    for (int i = 0; i < SEGLEN; ++i)
        e[i] = *reinterpret_cast<const float2*>(E + ebase + (size_t)i * CPAD);

    float vr = e[0].x, vi = e[0].y;
#pragma unroll
    for (int i = 1; i < SEGLEN; ++i) {
        const float nr = fmaf(Ar, vr, fmaf(-Ai, vi, e[i].x));
        const float ni = fmaf(Ar, vi, fmaf( Ai, vr, e[i].y));
        vr = nr; vi = ni;
    }

    *reinterpret_cast<float2*>(G + (((size_t)b * NSEG + seg) * 512 + r) * 2) =
        make_float2(vr, vi);
}

// Kernel 2b: fold segment-prefix from G, replay segment writing exclusive
// per-chunk prefixes to Hin. Same shape/coalescing as 2a.
// S_seg = sum_{k<seg} A_seg^(seg-1-k) G[k], A_seg = a^(CLEN*SEGLEN) (fp64 once).
__global__ __launch_bounds__(512, 4)
void ssm_seg_scan(const float* __restrict__ E,
                  const float* __restrict__ G,
                  const float* __restrict__ lam,
                  const float* __restrict__ aph,
                  float* __restrict__ Hin) {
    const int b   = blockIdx.x >> 4;
    const int seg = blockIdx.x & (NSEG - 1);
    const int r   = threadIdx.x;
    const int d   = (r >> 3) * 4 + ((r >> 1) & 3);
    const int s   = r & 1;

    const double lm = (double)lam[d * 2 + s];
    const double ph = (double)aph[d * 2 + s];
    const double mL = exp(lm * (double)CLEN);
    const double pL = ph * (double)CLEN;
    const float Ar = (float)(mL * cos(pL));                    // A_L
    const float Ai = (float)(mL * sin(pL));
    const double mS = exp(lm * (double)(CLEN * SEGLEN));
    const double pS = ph * (double)(CLEN * SEGLEN);
    const float Sr = (float)(mS * cos(pS));                    // A_seg
    const float Si = (float)(mS * sin(pS));

    // pre-issue all G loads (fixed trip -> registers), fold predicated k<seg
    float2 g[NSEG];
#pragma unroll
    for (int k = 0; k < NSEG; ++k)
        g[k] = *reinterpret_cast<const float2*>(G + (((size_t)b * NSEG + k) * 512 + r) * 2);

    // pre-issue all segment e loads
    const size_t ebase = ((size_t)b * CHUNKS + (size_t)seg * SEGLEN) * CPAD + (size_t)r * 2;
    float2 e[SEGLEN];
#pragma unroll
    for (int i = 0; i < SEGLEN; ++i)
        e[i] = *reinterpret_cast<const float2*>(E + ebase + (size_t)i * CPAD);

    float pr = 0.f, pi = 0.f;
#pragma unroll
    for (int k = 0; k < NSEG; ++k) {
        if (k < seg) {
            const float nr = fmaf(Sr, pr, fmaf(-Si, pi, g[k].x));
            const float ni = fmaf(Sr, pi, fmaf( Si, pr, g[k].y));
            pr = nr; pi = ni;
        }
    }

#pragma unroll
    for (int i = 0; i < SEGLEN; ++i) {
        *reinterpret_cast<float2*>(Hin + ebase + (size_t)i * CPAD) =
            make_float2(pr, pi);
        const float nr = fmaf(Ar, pr, fmaf(-Ai, pi, e[i].x));
        const float ni = fmaf(Ar, pi, fmaf( Ai, pr, e[i].y));
        pr = nr; pi = ni;
    }
}

// Kernel 3: replay local recurrence seeded from Hin; fuse output projection.
// Same pre-issued xv[16] MLP fix as K1.
__global__ __launch_bounds__(256, 3)
void ssm_output(const float* __restrict__ x,
                const float* __restrict__ lam,
                const float* __restrict__ aph,
                const float* __restrict__ Bre,
                const float* __restrict__ Bim,
                const float* __restrict__ Cre,
                const float* __restrict__ Cim,
                const float* __restrict__ Dd,
                const float* __restrict__ Hin,
                float* __restrict__ y) {
    const int lane = threadIdx.x & 63;
    const int w    = threadIdx.x >> 6;
    const int bid  = blockIdx.x;
    const int b    = bid >> 7;
    const int c    = ((bid & 127) << 2) + w;
    const int d0   = lane * 4;

    const size_t tbase = ((size_t)b * SEQ + (size_t)c * CLEN) * DMODEL + d0;
    const float* xp = x + tbase;
    float4 xv[CLEN];
#pragma unroll
    for (int t = 0; t < CLEN; ++t)
        xv[t] = *reinterpret_cast<const float4*>(xp + (size_t)t * DMODEL);

    float hr[4][2], hi[4][2];
    const float* hp = Hin + ((size_t)b * CHUNKS + c) * CPAD + lane * 16;
#pragma unroll
    for (int j = 0; j < 4; ++j) {
        const float4 v = reinterpret_cast<const float4*>(hp)[j];
        hr[j][0] = v.x; hi[j][0] = v.y;
        hr[j][1] = v.z; hi[j][1] = v.w;
    }

    float ar[4][2], ai[4][2], br[4][2], bi[4][2], cr[4][2], ci[4][2], dd[4];
#pragma unroll
    for (int j = 0; j < 4; ++j) {
        const int d = d0 + j;
        dd[j] = Dd[d];
#pragma unroll
        for (int s = 0; s < 2; ++s) {
            const float lm = lam[d * 2 + s];
            const float ph = aph[d * 2 + s];
            const float m  = expf(lm);
            ar[j][s] = m * cosf(ph);
            ai[j][s] = m * sinf(ph);
            br[j][s] = Bre[d * 2 + s];
            bi[j][s] = Bim[d * 2 + s];
            cr[j][s] = Cre[d * 2 + s];
            ci[j][s] = Cim[d * 2 + s];
        }
    }

    float* yp = y + tbase;
#pragma unroll
    for (int t = 0; t < CLEN; ++t) {
        const float xj[4] = {xv[t].x, xv[t].y, xv[t].z, xv[t].w};
        float yj[4];
#pragma unroll
        for (int j = 0; j < 4; ++j) {
            float acc = dd[j] * xj[j];
#pragma unroll
            for (int s = 0; s < 2; ++s) {
                const float nr = fmaf(ar[j][s], hr[j][s],
                                 fmaf(-ai[j][s], hi[j][s], br[j][s] * xj[j]));
                const float ni = fmaf(ar[j][s], hi[j][s],
                                 fmaf( ai[j][s], hr[j][s], bi[j][s] * xj[j]));
                hr[j][s] = nr;
                hi[j][s] = ni;
                acc = fmaf(cr[j][s], nr, acc);
                acc = fmaf(-ci[j][s], ni, acc);
            }
            yj[j] = acc;
        }
        floatx4 yv;
        yv.x = yj[0]; yv.y = yj[1]; yv.z = yj[2]; yv.w = yj[3];
        // y is never re-read: nontemporal store keeps x L3-resident.
        __builtin_nontemporal_store(yv,
            reinterpret_cast<floatx4*>(yp + (size_t)t * DMODEL));
    }
}

extern "C" void kernel_launch(void* const* d_in, const int* in_sizes, int n_in,
                              void* d_out, int out_size, void* d_ws, size_t ws_size,
                              hipStream_t stream) {
    const float* x   = (const float*)d_in[0];
    const float* lam = (const float*)d_in[1];
    const float* aph = (const float*)d_in[2];
    const float* Bre = (const float*)d_in[3];
    const float* Bim = (const float*)d_in[4];
    const float* Cre = (const float*)d_in[5];
    const float* Cim = (const float*)d_in[6];
    const float* Dd  = (const float*)d_in[7];
    float* yo = (float*)d_out;

    float* E   = (float*)d_ws;                                    // ~17 MB
    float* Hin = E + (size_t)BATCH * CHUNKS * CPAD;               // ~17 MB
    float* G   = Hin + (size_t)BATCH * CHUNKS * CPAD;             // 512 KB

    ssm_chunk_state<<<BATCH * CHUNKS / 4, 256, 0, stream>>>(x, lam, aph, Bre, Bim, E);
    ssm_seg_aggregate<<<BATCH * NSEG, 512, 0, stream>>>(E, lam, aph, G);
    ssm_seg_scan<<<BATCH * NSEG, 512, 0, stream>>>(E, G, lam, aph, Hin);
    ssm_output<<<BATCH * CHUNKS / 4, 256, 0, stream>>>(x, lam, aph, Bre, Bim,
                                                       Cre, Cim, Dd, Hin, yo);
}

// Round 3
// 145.228 us; speedup vs baseline: 1.5035x; 1.5035x over previous
//
#include <hip/hip_runtime.h>
#include <math.h>

#define BATCH  8
#define SEQ    8192
#define DMODEL 256
#define DSTATE 2
#define CHUNKS 256   // C (round-0 depth: halves E/Hin traffic vs CHUNKS=512)
#define CLEN   32    // L = SEQ / C
#define CPAD   1040  // floats per (b,c) block: 1024 data + 16 pad (16B-aligned rows)
#define NSEG   16    // segments per batch-scan
#define SEGLEN 16    // chunks per segment = CHUNKS / NSEG

// ---------------------------------------------------------------------------
// Parallelization change (round 3): ONE channel per thread (was 4).
//   K1/K3: 2048 blocks x 256 threads, block = chunk (b,c), thread = channel d.
//   -> 8192 waves = 32 waves/CU = 100% occupancy. The 2.4 TB/s plateau in
//   rounds 0-2 was TLP-limited (serial recurrence, 8-16 waves/CU); per-wave
//   MLP tricks (round 2 pre-issue) regressed it. BW scales with waves.
// Layouts:
//   x, y : [B][T][D] fp32
//   E / Hin workspace: [B][C][CPAD] floats (first 1024 used)
//     thread d owns float4 {s0re, s0im, s1re, s1im} at float-offset d*4.
//     scan slot r = d*2 + s -> float2 at float-offset 2r.
//   G: [B][NSEG][512] float2 segment aggregates (512 KB)
// Recurrence: h[t] = a h[t-1] + B x[t], a = e^{lm}(cos ph + i sin ph)
// y[t,d] = sum_s Re(C h) + D_diag x
// ---------------------------------------------------------------------------

// Kernel 1: per-chunk local end state (zero init).
__global__ __launch_bounds__(256, 8)
void ssm_chunk_state(const float* __restrict__ x,
                     const float* __restrict__ lam,
                     const float* __restrict__ aph,
                     const float* __restrict__ Bre,
                     const float* __restrict__ Bim,
                     float* __restrict__ E) {
    const int d   = threadIdx.x;
    const int bid = blockIdx.x;
    const int b   = bid >> 8;
    const int c   = bid & (CHUNKS - 1);

    const float2 lm2 = *reinterpret_cast<const float2*>(lam + d * 2);
    const float2 ph2 = *reinterpret_cast<const float2*>(aph + d * 2);
    const float2 br2 = *reinterpret_cast<const float2*>(Bre + d * 2);
    const float2 bi2 = *reinterpret_cast<const float2*>(Bim + d * 2);
    const float m0 = expf(lm2.x), m1 = expf(lm2.y);
    const float ar0 = m0 * cosf(ph2.x), ai0 = m0 * sinf(ph2.x);
    const float ar1 = m1 * cosf(ph2.y), ai1 = m1 * sinf(ph2.y);
    const float br0 = br2.x, br1 = br2.y, bi0 = bi2.x, bi1 = bi2.y;

    float hr0 = 0.f, hi0 = 0.f, hr1 = 0.f, hi1 = 0.f;
    const float* xp = x + ((size_t)b * SEQ + (size_t)c * CLEN) * DMODEL + d;
#pragma unroll 8
    for (int t = 0; t < CLEN; ++t) {
        const float xt = xp[(size_t)t * DMODEL];
        const float bx0 = br0 * xt, by0 = bi0 * xt;
        const float bx1 = br1 * xt, by1 = bi1 * xt;
        const float n0r = fmaf(ar0, hr0, fmaf(-ai0, hi0, bx0));
        const float n0i = fmaf(ar0, hi0, fmaf( ai0, hr0, by0));
        const float n1r = fmaf(ar1, hr1, fmaf(-ai1, hi1, bx1));
        const float n1i = fmaf(ar1, hi1, fmaf( ai1, hr1, by1));
        hr0 = n0r; hi0 = n0i; hr1 = n1r; hi1 = n1i;
    }

    float4 ev;
    ev.x = hr0; ev.y = hi0; ev.z = hr1; ev.w = hi1;
    *reinterpret_cast<float4*>(E + ((size_t)b * CHUNKS + c) * CPAD + d * 4) = ev;
}

// Kernel 2a: segment aggregates, fully coalesced.
// 256 blocks (b, seg, half) x 256 threads; thread owns scan slot
// r = half*256+tid, serially folds its segment's 16 chunk states.
// G[b][seg][r] = sum_i A_L^(SEGLEN-1-i) e[seg*SEGLEN+i].
__global__ __launch_bounds__(256, 4)
void ssm_seg_aggregate(const float* __restrict__ E,
                       const float* __restrict__ lam,
                       const float* __restrict__ aph,
                       float* __restrict__ G) {
    const int bid  = blockIdx.x;
    const int b    = bid >> 5;
    const int seg  = (bid >> 1) & (NSEG - 1);
    const int r    = ((bid & 1) << 8) + threadIdx.x;
    const int d    = r >> 1;
    const int s    = r & 1;

    const double lm = (double)lam[d * 2 + s];
    const double ph = (double)aph[d * 2 + s];
    const double mL = exp(lm * (double)CLEN);
    const double pL = ph * (double)CLEN;
    const float Ar = (float)(mL * cos(pL));   // A_L = a^CLEN
    const float Ai = (float)(mL * sin(pL));

    const size_t ebase =
        ((size_t)b * CHUNKS + (size_t)seg * SEGLEN) * CPAD + (size_t)r * 2;

    float2 e[SEGLEN];
#pragma unroll
    for (int i = 0; i < SEGLEN; ++i)
        e[i] = *reinterpret_cast<const float2*>(E + ebase + (size_t)i * CPAD);

    float vr = e[0].x, vi = e[0].y;
#pragma unroll
    for (int i = 1; i < SEGLEN; ++i) {
        const float nr = fmaf(Ar, vr, fmaf(-Ai, vi, e[i].x));
        const float ni = fmaf(Ar, vi, fmaf( Ai, vr, e[i].y));
        vr = nr; vi = ni;
    }

    *reinterpret_cast<float2*>(G + (((size_t)b * NSEG + seg) * 512 + r) * 2) =
        make_float2(vr, vi);
}

// Kernel 2b: fold segment-prefix from G, replay segment writing exclusive
// per-chunk prefixes to Hin. Same shape/coalescing as 2a.
// S_seg = sum_{k<seg} A_seg^(seg-1-k) G[k], A_seg = a^(CLEN*SEGLEN) (fp64 once).
__global__ __launch_bounds__(256, 4)
void ssm_seg_scan(const float* __restrict__ E,
                  const float* __restrict__ G,
                  const float* __restrict__ lam,
                  const float* __restrict__ aph,
                  float* __restrict__ Hin) {
    const int bid  = blockIdx.x;
    const int b    = bid >> 5;
    const int seg  = (bid >> 1) & (NSEG - 1);
    const int r    = ((bid & 1) << 8) + threadIdx.x;
    const int d    = r >> 1;
    const int s    = r & 1;

    const double lm = (double)lam[d * 2 + s];
    const double ph = (double)aph[d * 2 + s];
    const double mL = exp(lm * (double)CLEN);
    const double pL = ph * (double)CLEN;
    const float Ar = (float)(mL * cos(pL));                    // A_L
    const float Ai = (float)(mL * sin(pL));
    const double mS = exp(lm * (double)(CLEN * SEGLEN));
    const double pS = ph * (double)(CLEN * SEGLEN);
    const float Sr = (float)(mS * cos(pS));                    // A_seg
    const float Si = (float)(mS * sin(pS));

    float2 g[NSEG];
#pragma unroll
    for (int k = 0; k < NSEG; ++k)
        g[k] = *reinterpret_cast<const float2*>(
            G + (((size_t)b * NSEG + k) * 512 + r) * 2);

    const size_t ebase =
        ((size_t)b * CHUNKS + (size_t)seg * SEGLEN) * CPAD + (size_t)r * 2;
    float2 e[SEGLEN];
#pragma unroll
    for (int i = 0; i < SEGLEN; ++i)
        e[i] = *reinterpret_cast<const float2*>(E + ebase + (size_t)i * CPAD);

    float pr = 0.f, pi = 0.f;
#pragma unroll
    for (int k = 0; k < NSEG; ++k) {
        if (k < seg) {   // seg is block-uniform -> non-divergent
            const float nr = fmaf(Sr, pr, fmaf(-Si, pi, g[k].x));
            const float ni = fmaf(Sr, pi, fmaf( Si, pr, g[k].y));
            pr = nr; pi = ni;
        }
    }

#pragma unroll
    for (int i = 0; i < SEGLEN; ++i) {
        *reinterpret_cast<float2*>(Hin + ebase + (size_t)i * CPAD) =
            make_float2(pr, pi);
        const float nr = fmaf(Ar, pr, fmaf(-Ai, pi, e[i].x));
        const float ni = fmaf(Ar, pi, fmaf( Ai, pr, e[i].y));
        pr = nr; pi = ni;
    }
}

// Kernel 3: replay local recurrence seeded from Hin; fuse output projection.
__global__ __launch_bounds__(256, 8)
void ssm_output(const float* __restrict__ x,
                const float* __restrict__ lam,
                const float* __restrict__ aph,
                const float* __restrict__ Bre,
                const float* __restrict__ Bim,
                const float* __restrict__ Cre,
                const float* __restrict__ Cim,
                const float* __restrict__ Dd,
                const float* __restrict__ Hin,
                float* __restrict__ y) {
    const int d   = threadIdx.x;
    const int bid = blockIdx.x;
    const int b   = bid >> 8;
    const int c   = bid & (CHUNKS - 1);

    const float4 hv = *reinterpret_cast<const float4*>(
        Hin + ((size_t)b * CHUNKS + c) * CPAD + d * 4);
    float hr0 = hv.x, hi0 = hv.y, hr1 = hv.z, hi1 = hv.w;

    const float2 lm2 = *reinterpret_cast<const float2*>(lam + d * 2);
    const float2 ph2 = *reinterpret_cast<const float2*>(aph + d * 2);
    const float2 br2 = *reinterpret_cast<const float2*>(Bre + d * 2);
    const float2 bi2 = *reinterpret_cast<const float2*>(Bim + d * 2);
    const float2 cr2 = *reinterpret_cast<const float2*>(Cre + d * 2);
    const float2 ci2 = *reinterpret_cast<const float2*>(Cim + d * 2);
    const float dd  = Dd[d];
    const float m0 = expf(lm2.x), m1 = expf(lm2.y);
    const float ar0 = m0 * cosf(ph2.x), ai0 = m0 * sinf(ph2.x);
    const float ar1 = m1 * cosf(ph2.y), ai1 = m1 * sinf(ph2.y);
    const float br0 = br2.x, br1 = br2.y, bi0 = bi2.x, bi1 = bi2.y;
    const float cr0 = cr2.x, cr1 = cr2.y, ci0 = ci2.x, ci1 = ci2.y;

    const size_t tbase = ((size_t)b * SEQ + (size_t)c * CLEN) * DMODEL + d;
    const float* xp = x + tbase;
    float* yp = y + tbase;
#pragma unroll 8
    for (int t = 0; t < CLEN; ++t) {
        const float xt = xp[(size_t)t * DMODEL];
        const float n0r = fmaf(ar0, hr0, fmaf(-ai0, hi0, br0 * xt));
        const float n0i = fmaf(ar0, hi0, fmaf( ai0, hr0, bi0 * xt));
        const float n1r = fmaf(ar1, hr1, fmaf(-ai1, hi1, br1 * xt));
        const float n1i = fmaf(ar1, hi1, fmaf( ai1, hr1, bi1 * xt));
        hr0 = n0r; hi0 = n0i; hr1 = n1r; hi1 = n1i;
        float acc = dd * xt;
        acc = fmaf(cr0, n0r, acc);
        acc = fmaf(-ci0, n0i, acc);
        acc = fmaf(cr1, n1r, acc);
        acc = fmaf(-ci1, n1i, acc);
        // y is never re-read: nontemporal store keeps x L3-resident.
        __builtin_nontemporal_store(acc, yp + (size_t)t * DMODEL);
    }
}

extern "C" void kernel_launch(void* const* d_in, const int* in_sizes, int n_in,
                              void* d_out, int out_size, void* d_ws, size_t ws_size,
                              hipStream_t stream) {
    const float* x   = (const float*)d_in[0];
    const float* lam = (const float*)d_in[1];
    const float* aph = (const float*)d_in[2];
    const float* Bre = (const float*)d_in[3];
    const float* Bim = (const float*)d_in[4];
    const float* Cre = (const float*)d_in[5];
    const float* Cim = (const float*)d_in[6];
    const float* Dd  = (const float*)d_in[7];
    float* yo = (float*)d_out;

    float* E   = (float*)d_ws;                                    // ~8.5 MB
    float* Hin = E + (size_t)BATCH * CHUNKS * CPAD;               // ~8.5 MB
    float* G   = Hin + (size_t)BATCH * CHUNKS * CPAD;             // 512 KB

    ssm_chunk_state<<<BATCH * CHUNKS, 256, 0, stream>>>(x, lam, aph, Bre, Bim, E);
    ssm_seg_aggregate<<<BATCH * NSEG * 2, 256, 0, stream>>>(E, lam, aph, G);
    ssm_seg_scan<<<BATCH * NSEG * 2, 256, 0, stream>>>(E, G, lam, aph, Hin);
    ssm_output<<<BATCH * CHUNKS, 256, 0, stream>>>(x, lam, aph, Bre, Bim,
                                                   Cre, Cim, Dd, Hin, yo);
}